// Round 6
// baseline (575.601 us; speedup 1.0000x reference)
//
#include <hip/hip_runtime.h>

#define D 128
#define R_REL 10
#define NBASE 4
#define NC 12
#define LN_EPS 1e-5f

typedef __attribute__((ext_vector_type(8))) short short8;
typedef __attribute__((ext_vector_type(4))) float f32x4;

static __device__ __forceinline__ unsigned short f2bf(float f) {
    unsigned u = __float_as_uint(f);
    unsigned r = (u + 0x7FFFu + ((u >> 16) & 1u)) >> 16;   // RNE
    return (unsigned short)r;
}

// ---------------- fallback f32 -> xb bf16 ----------------
__global__ void k_copy_bf(const float4* __restrict__ src, uint2* __restrict__ dst, int n4) {
    int i = blockIdx.x * blockDim.x + threadIdx.x;
    if (i < n4) {
        float4 v = src[i];
        uint2 o;
        o.x = (unsigned)f2bf(v.x) | ((unsigned)f2bf(v.y) << 16);
        o.y = (unsigned)f2bf(v.z) | ((unsigned)f2bf(v.w) << 16);
        dst[i] = o;
    }
}

// ---------------- typed projection: xb[idx[m]] = bf16(feats[m] @ W + b) ----------------
__global__ void k_proj8(const float* __restrict__ feats, const float* __restrict__ W,
                        const float* __restrict__ bias, const int* __restrict__ idx,
                        unsigned short* __restrict__ xb, int M, int K) {
    __shared__ float lds[8 * 256];
    int m0 = blockIdx.x * 8;
    int rows = M - m0; if (rows > 8) rows = 8;
    for (int i = threadIdx.x; i < rows * K; i += 128) {
        int r = i / K, k = i - r * K;
        lds[r * K + k] = feats[(size_t)(m0 + r) * K + k];
    }
    __syncthreads();
    int o = threadIdx.x;  // 0..127 output col
    float bz = bias[o];
    float acc[8];
#pragma unroll
    for (int r = 0; r < 8; ++r) acc[r] = bz;
    for (int k = 0; k < K; ++k) {
        float wv = W[k * D + o];
#pragma unroll
        for (int r = 0; r < 8; ++r) acc[r] = fmaf(lds[r * K + k], wv, acc[r]);
    }
#pragma unroll
    for (int r = 0; r < 8; ++r) {
        if (r < rows) xb[(size_t)idx[m0 + r] * D + o] = f2bf(acc[r]);
    }
}

// ---------------- degree histogram ----------------
__global__ void k_deg(const int* __restrict__ ei, int* __restrict__ deg, int E) {
    int e = blockIdx.x * blockDim.x + threadIdx.x;
    if (e < E) atomicAdd(&deg[ei[E + e]], 1);
}

// ---------------- exclusive scan (3 kernels) ----------------
#define SCAN_B 256
__global__ void k_scan1(const int* __restrict__ deg, int* __restrict__ off,
                        int* __restrict__ bsum, int n) {
    __shared__ int lds[SCAN_B];
    int i = blockIdx.x * SCAN_B + threadIdx.x;
    int v = (i < n) ? deg[i] : 0;
    lds[threadIdx.x] = v; __syncthreads();
    for (int s = 1; s < SCAN_B; s <<= 1) {
        int t = (threadIdx.x >= s) ? lds[threadIdx.x - s] : 0;
        __syncthreads();
        lds[threadIdx.x] += t;
        __syncthreads();
    }
    if (i < n) off[i] = lds[threadIdx.x] - v;  // exclusive
    if (threadIdx.x == SCAN_B - 1) bsum[blockIdx.x] = lds[threadIdx.x];
}
__global__ void k_scan2(int* __restrict__ bsum, int nb) {
    __shared__ int lds[SCAN_B];
    int v = (threadIdx.x < nb) ? bsum[threadIdx.x] : 0;
    lds[threadIdx.x] = v; __syncthreads();
    for (int s = 1; s < SCAN_B; s <<= 1) {
        int t = (threadIdx.x >= s) ? lds[threadIdx.x - s] : 0;
        __syncthreads();
        lds[threadIdx.x] += t;
        __syncthreads();
    }
    if (threadIdx.x < nb) bsum[threadIdx.x] = lds[threadIdx.x] - v;
}
__global__ void k_scan3(int* __restrict__ off, const int* __restrict__ bsum,
                        int* __restrict__ cursor, int n) {
    int i = blockIdx.x * SCAN_B + threadIdx.x;
    if (i < n) {
        int o = off[i] + bsum[blockIdx.x];
        off[i] = o;
        cursor[i] = o;
    }
}

// ---------------- CSR fill: csr[p] = src | etype<<16 ----------------
__global__ void k_fill(const int* __restrict__ ei, const int* __restrict__ et,
                       int* __restrict__ cursor, unsigned* __restrict__ csr, int E) {
    int e = blockIdx.x * blockDim.x + threadIdx.x;
    if (e < E) {
        int d = ei[E + e];
        int p = atomicAdd(&cursor[d], 1);
        csr[p] = (unsigned)ei[e] | ((unsigned)et[e] << 16);
    }
}

// ---------------- aggregation: Zb[n, b*128+d] = bf16( sum_r comp[r,b]*mean[r,n,d] ) ----
// one node per wave. Register accumulators (et is wave-uniform -> scalar branch chain).
// csr read 64-wide per wave; 1-deep prefetch of the gathered x row. No LDS, no barriers.
__global__ void k_agg(const unsigned short* __restrict__ xb, const int* __restrict__ off,
                      const int* __restrict__ deg, const unsigned* __restrict__ csr,
                      const float* __restrict__ comp, unsigned short* __restrict__ Zb, int Nn) {
    int w = threadIdx.x >> 6;
    int lane = threadIdx.x & 63;
    int n = blockIdx.x * 4 + w;
    if (n >= Nn) return;

    int start = off[n];
    int dg = deg[n];
    float ax[R_REL], ay[R_REL];
#pragma unroll
    for (int r = 0; r < R_REL; ++r) { ax[r] = 0.f; ay[r] = 0.f; }
    int myCnt = 0;  // lane r counts edges of relation r

    const unsigned* cp = csr + start;
    for (int j0 = 0; j0 < dg; j0 += 64) {
        int m = dg - j0; if (m > 64) m = 64;
        unsigned myU = (j0 + lane < dg) ? cp[j0 + lane] : 0u;   // one coalesced load / 64 edges
        unsigned u = __shfl(myU, 0, 64);
        int src0 = __builtin_amdgcn_readfirstlane((int)(u & 0xFFFFu));
        unsigned xv = *(const unsigned*)&xb[(size_t)src0 * D + lane * 2];
        for (int jj = 0; jj < m; ++jj) {
            unsigned uc = u, xc = xv;
            if (jj + 1 < m) {     // prefetch next edge's row
                u = __shfl(myU, jj + 1, 64);
                int s2 = (int)(u & 0xFFFFu);
                xv = *(const unsigned*)&xb[(size_t)s2 * D + lane * 2];
            }
            int et = __builtin_amdgcn_readfirstlane((int)(uc >> 16));  // wave-uniform SGPR
            float vx = __uint_as_float(xc << 16);
            float vy = __uint_as_float(xc & 0xFFFF0000u);
#pragma unroll
            for (int r = 0; r < R_REL; ++r)
                if (et == r) { ax[r] += vx; ay[r] += vy; }   // scalar-branch, 2 v_add taken
            if (lane == et) myCnt++;
        }
    }

    float inv[R_REL];
#pragma unroll
    for (int r = 0; r < R_REL; ++r) {
        int c = __shfl(myCnt, r, 64);
        inv[r] = (c > 0) ? (1.f / (float)c) : 1.f;   // max(cnt,1)
    }
#pragma unroll
    for (int b = 0; b < NBASE; ++b) {
        float zx = 0.f, zy = 0.f;
#pragma unroll
        for (int r = 0; r < R_REL; ++r) {
            float cc = comp[r * NBASE + b];    // uniform -> s_load
            zx = fmaf(cc, ax[r] * inv[r], zx);
            zy = fmaf(cc, ay[r] * inv[r], zy);
        }
        unsigned o = (unsigned)f2bf(zx) | ((unsigned)f2bf(zy) << 16);
        *(unsigned*)&Zb[(size_t)n * 512 + b * D + lane * 2] = o;
    }
}

// ---------------- B panel transpose+cast: BT[n][k] = bf16([bases;root][k][n]) ----------
__global__ void k_bt(const float* __restrict__ bases, const float* __restrict__ root,
                     unsigned short* __restrict__ BT) {
    int i = blockIdx.x * 256 + threadIdx.x;       // over 128*640
    if (i >= 128 * 640) return;
    int n = i / 640, k = i - n * 640;
    float v = (k < 512) ? bases[(size_t)k * D + n] : root[(size_t)(k - 512) * D + n];
    BT[i] = f2bf(v);
}

// ---------------- MFMA layer GEMM: P = [Zb | xb] @ BT^T + bias ----------------
// M rows, K=640, N=128. BM=64, 256 threads = 4 waves, each wave 32x64.
// Double-buffered LDS, global->reg prefetch before MFMAs, ONE barrier per K-step.
// LDS rows padded to 80B (5 x 16B slots) -> <=2-way bank aliasing.
__global__ void k_gemm_mfma(const unsigned short* __restrict__ Zb,
                            const unsigned short* __restrict__ xb,
                            const unsigned short* __restrict__ BT,
                            const float* __restrict__ bias,
                            float* __restrict__ P, int M) {
    __shared__ unsigned short As[2][64 * 40];    // 10 KB
    __shared__ unsigned short Bs[2][128 * 40];   // 20.5 KB
    int t = threadIdx.x;
    int l = t & 63;
    int w = t >> 6;
    int wm = w & 1;               // 32-row half
    int wn = (w >> 1) * 64;       // 64-col half
    int m0 = blockIdx.x * 64;
    int lrow = l & 15;
    int kq = l >> 4;              // 0..3

    f32x4 acc[2][4];
#pragma unroll
    for (int s = 0; s < 2; ++s)
#pragma unroll
        for (int ct = 0; ct < 4; ++ct) acc[s][ct] = (f32x4){0.f, 0.f, 0.f, 0.f};

    // staging assignments: A 64x32 tile, 8 bf16 (16B) per thread
    int arow = t >> 2, ako = (t & 3) * 8;
    // B 128x32 tile, 16 bf16 (32B) per thread
    int brow = t >> 1, bko = (t & 1) * 16;
    int arg = m0 + arow; if (arg >= M) arg = M - 1;

    uint4 aR, bR0, bR1;
    auto gload = [&](int k0) {
        const unsigned short* asrc = (k0 < 512)
            ? &Zb[(size_t)arg * 512 + k0 + ako]
            : &xb[(size_t)arg * D + (k0 - 512) + ako];
        aR = *(const uint4*)asrc;
        const unsigned short* bsrc = &BT[(size_t)brow * 640 + k0 + bko];
        bR0 = *(const uint4*)bsrc;
        bR1 = *(const uint4*)(bsrc + 8);
    };
    auto sstore = [&](int p) {
        *(uint4*)&As[p][arow * 40 + ako] = aR;
        *(uint4*)&Bs[p][brow * 40 + bko] = bR0;
        *(uint4*)&Bs[p][brow * 40 + bko + 8] = bR1;
    };

    gload(0);
    sstore(0);
    int p = 0;
    for (int k0 = 0; k0 < 640; k0 += 32) {
        __syncthreads();                       // buf[p] ready for all waves
        if (k0 + 32 < 640) gload(k0 + 32);     // issue next-tile loads (overlap MFMA)
        short8 a0 = *(const short8*)&As[p][(wm * 32 + lrow) * 40 + kq * 8];
        short8 a1 = *(const short8*)&As[p][(wm * 32 + 16 + lrow) * 40 + kq * 8];
#pragma unroll
        for (int ct = 0; ct < 4; ++ct) {
            short8 b = *(const short8*)&Bs[p][(wn + ct * 16 + lrow) * 40 + kq * 8];
            acc[0][ct] = __builtin_amdgcn_mfma_f32_16x16x32_bf16(a0, b, acc[0][ct], 0, 0, 0);
            acc[1][ct] = __builtin_amdgcn_mfma_f32_16x16x32_bf16(a1, b, acc[1][ct], 0, 0, 0);
        }
        if (k0 + 32 < 640) { sstore(p ^ 1); p ^= 1; }
    }

    int r0 = m0 + wm * 32 + kq * 4;
#pragma unroll
    for (int sub = 0; sub < 2; ++sub) {
#pragma unroll
        for (int ct = 0; ct < 4; ++ct) {
            int col = wn + ct * 16 + lrow;
            float bv = bias[col];
#pragma unroll
            for (int r = 0; r < 4; ++r) {
                int rg = r0 + sub * 16 + r;
                if (rg < M) P[(size_t)rg * D + col] = acc[sub][ct][r] + bv;
            }
        }
    }
}

// ---------------- LayerNorm + ReLU -> bf16 ----------------
__global__ void k_lnrelu(const float* __restrict__ P, const float* __restrict__ g,
                         const float* __restrict__ b, unsigned short* __restrict__ hb, int Nn) {
    int w = threadIdx.x >> 6, lane = threadIdx.x & 63;
    int n = blockIdx.x * 4 + w;
    if (n >= Nn) return;
    float2 v = *(const float2*)&P[(size_t)n * D + lane * 2];
    float s = v.x + v.y;
#pragma unroll
    for (int o = 1; o < 64; o <<= 1) s += __shfl_xor(s, o, 64);
    float m = s * (1.f / 128.f);
    float dx = v.x - m, dy = v.y - m;
    float vs = dx * dx + dy * dy;
#pragma unroll
    for (int o = 1; o < 64; o <<= 1) vs += __shfl_xor(vs, o, 64);
    float inv = rsqrtf(vs * (1.f / 128.f) + LN_EPS);
    float2 gg = *(const float2*)&g[lane * 2];
    float2 bb = *(const float2*)&b[lane * 2];
    float ox = fmaxf(dx * inv * gg.x + bb.x, 0.f);
    float oy = fmaxf(dy * inv * gg.y + bb.y, 0.f);
    unsigned o2 = (unsigned)f2bf(ox) | ((unsigned)f2bf(oy) << 16);
    *(unsigned*)&hb[(size_t)n * D + lane * 2] = o2;
}

// ---------------- final: gather + LN + relu(h@Wc1+bc1) @ Wc2 + bc2 ----------------
__global__ void k_final(const float* __restrict__ P2, const int* __restrict__ nidx,
                        const float* __restrict__ g, const float* __restrict__ b,
                        const float* __restrict__ Wc1, const float* __restrict__ bc1,
                        const float* __restrict__ Wc2, const float* __restrict__ bc2,
                        float* __restrict__ out, int M) {
    __shared__ float ln[D];
    __shared__ float t[D];
    __shared__ float red[2];
    int i = blockIdx.x;
    if (i >= M) return;
    int d = threadIdx.x;
    int n = nidx[i];
    float v = P2[(size_t)n * D + d];
    float s = v;
#pragma unroll
    for (int o = 1; o < 64; o <<= 1) s += __shfl_xor(s, o, 64);
    if ((d & 63) == 0) red[d >> 6] = s;
    __syncthreads();
    float m = (red[0] + red[1]) * (1.f / 128.f);
    __syncthreads();
    float dv = v - m;
    float vs = dv * dv;
#pragma unroll
    for (int o = 1; o < 64; o <<= 1) vs += __shfl_xor(vs, o, 64);
    if ((d & 63) == 0) red[d >> 6] = vs;
    __syncthreads();
    float inv = rsqrtf((red[0] + red[1]) * (1.f / 128.f) + LN_EPS);
    ln[d] = dv * inv * g[d] + b[d];
    __syncthreads();
    float a = bc1[d];
    for (int k = 0; k < D; ++k) a = fmaf(ln[k], Wc1[k * D + d], a);
    t[d] = fmaxf(a, 0.f);
    __syncthreads();
    if (d < NC) {
        float o2 = bc2[d];
        for (int k = 0; k < D; ++k) o2 = fmaf(t[k], Wc2[k * NC + d], o2);
        out[(size_t)i * NC + d] = o2;
    }
}

extern "C" void kernel_launch(void* const* d_in, const int* in_sizes, int n_in,
                              void* d_out, int out_size, void* d_ws, size_t ws_size,
                              hipStream_t stream) {
    const int*   edge_index   = (const int*)d_in[0];
    const int*   edge_type    = (const int*)d_in[1];
    const int*   node_indices = (const int*)d_in[2];
    const float* file_feats   = (const float*)d_in[3];
    const int*   file_idx     = (const int*)d_in[4];
    const float* domain_feats = (const float*)d_in[5];
    const int*   domain_idx   = (const int*)d_in[6];
    const float* ip_feats     = (const float*)d_in[7];
    const int*   ip_idx       = (const int*)d_in[8];
    const float* fallback     = (const float*)d_in[9];
    const float* Wf = (const float*)d_in[10]; const float* bf = (const float*)d_in[11];
    const float* Wd = (const float*)d_in[12]; const float* bd = (const float*)d_in[13];
    const float* Wi = (const float*)d_in[14]; const float* bi = (const float*)d_in[15];
    const float* comp1 = (const float*)d_in[16]; const float* bases1 = (const float*)d_in[17];
    const float* root1 = (const float*)d_in[18]; const float* bias1 = (const float*)d_in[19];
    const float* comp2 = (const float*)d_in[20]; const float* bases2 = (const float*)d_in[21];
    const float* root2 = (const float*)d_in[22]; const float* bias2 = (const float*)d_in[23];
    const float* ln1g = (const float*)d_in[24]; const float* ln1b = (const float*)d_in[25];
    const float* ln2g = (const float*)d_in[26]; const float* ln2b = (const float*)d_in[27];
    const float* Wc1 = (const float*)d_in[28]; const float* bc1 = (const float*)d_in[29];
    const float* Wc2 = (const float*)d_in[30]; const float* bc2 = (const float*)d_in[31];

    const int E  = in_sizes[1];
    const int Nn = in_sizes[9] / D;
    const int Mf = in_sizes[4], Kf = in_sizes[3] / Mf;
    const int Md = in_sizes[6], Kd = in_sizes[5] / Md;
    const int Mi = in_sizes[8], Ki = in_sizes[7] / Mi;
    const int Msel = in_sizes[2];

    char* w = (char*)d_ws;
    auto alloc = [&](size_t bytes) {
        char* p = w;
        w += (bytes + 255) & ~(size_t)255;
        return p;
    };
    unsigned short* xb  = (unsigned short*)alloc((size_t)Nn * D * 2);   // 12.8 MB
    unsigned short* h1b = (unsigned short*)alloc((size_t)Nn * D * 2);   // 12.8 MB
    float*          P   = (float*)alloc((size_t)Nn * D * 4);            // 25.6 MB
    unsigned short* Zb  = (unsigned short*)alloc((size_t)Nn * 512 * 2); // 51.2 MB
    unsigned short* BT1 = (unsigned short*)alloc((size_t)128 * 640 * 2);
    unsigned short* BT2 = (unsigned short*)alloc((size_t)128 * 640 * 2);
    int* deg    = (int*)alloc((size_t)Nn * 4);
    int* off    = (int*)alloc((size_t)Nn * 4);
    int* cursor = (int*)alloc((size_t)Nn * 4);
    int* bsum   = (int*)alloc(1024);
    unsigned* csr = (unsigned*)alloc((size_t)E * 4);                    // 3.2 MB

    hipMemsetAsync(deg, 0, (size_t)Nn * 4, stream);

    // node features (bf16)
    int n4 = Nn * D / 4;
    k_copy_bf<<<(n4 + 255) / 256, 256, 0, stream>>>((const float4*)fallback, (uint2*)xb, n4);
    k_proj8<<<(Mf + 7) / 8, 128, 0, stream>>>(file_feats, Wf, bf, file_idx, xb, Mf, Kf);
    k_proj8<<<(Md + 7) / 8, 128, 0, stream>>>(domain_feats, Wd, bd, domain_idx, xb, Md, Kd);
    k_proj8<<<(Mi + 7) / 8, 128, 0, stream>>>(ip_feats, Wi, bi, ip_idx, xb, Mi, Ki);

    // B panels (bf16, transposed)
    int nbt = (128 * 640 + 255) / 256;
    k_bt<<<nbt, 256, 0, stream>>>(bases1, root1, BT1);
    k_bt<<<nbt, 256, 0, stream>>>(bases2, root2, BT2);

    // CSR by dst (shared by both layers)
    k_deg<<<(E + 255) / 256, 256, 0, stream>>>(edge_index, deg, E);
    int nb = (Nn + SCAN_B - 1) / SCAN_B;
    k_scan1<<<nb, SCAN_B, 0, stream>>>(deg, off, bsum, Nn);
    k_scan2<<<1, SCAN_B, 0, stream>>>(bsum, nb);
    k_scan3<<<nb, SCAN_B, 0, stream>>>(off, bsum, cursor, Nn);
    k_fill<<<(E + 255) / 256, 256, 0, stream>>>(edge_index, edge_type, cursor, csr, E);

    int gemmGrid = (Nn + 63) / 64;

    // layer 1
    k_agg<<<(Nn + 3) / 4, 256, 0, stream>>>(xb, off, deg, csr, comp1, Zb, Nn);
    k_gemm_mfma<<<gemmGrid, 256, 0, stream>>>(Zb, xb, BT1, bias1, P, Nn);
    k_lnrelu<<<(Nn + 3) / 4, 256, 0, stream>>>(P, ln1g, ln1b, h1b, Nn);

    // layer 2
    k_agg<<<(Nn + 3) / 4, 256, 0, stream>>>(h1b, off, deg, csr, comp2, Zb, Nn);
    k_gemm_mfma<<<gemmGrid, 256, 0, stream>>>(Zb, h1b, BT2, bias2, P, Nn);

    // head
    k_final<<<Msel, 128, 0, stream>>>(P, node_indices, ln2g, ln2b, Wc1, bc1, Wc2, bc2,
                                      (float*)d_out, Msel);
}

// Round 8
// 546.897 us; speedup vs baseline: 1.0525x; 1.0525x over previous
//
#include <hip/hip_runtime.h>

#define D 128
#define R_REL 10
#define NBASE 4
#define NC 12
#define LN_EPS 1e-5f

typedef __attribute__((ext_vector_type(8))) short short8;
typedef __attribute__((ext_vector_type(4))) float f32x4;

static __device__ __forceinline__ unsigned short f2bf(float f) {
    unsigned u = __float_as_uint(f);
    unsigned r = (u + 0x7FFFu + ((u >> 16) & 1u)) >> 16;   // RNE
    return (unsigned short)r;
}

// ---------------- fallback f32 -> xb bf16 ----------------
__global__ void k_copy_bf(const float4* __restrict__ src, uint2* __restrict__ dst, int n4) {
    int i = blockIdx.x * blockDim.x + threadIdx.x;
    if (i < n4) {
        float4 v = src[i];
        uint2 o;
        o.x = (unsigned)f2bf(v.x) | ((unsigned)f2bf(v.y) << 16);
        o.y = (unsigned)f2bf(v.z) | ((unsigned)f2bf(v.w) << 16);
        dst[i] = o;
    }
}

// ---------------- typed projection: xb[idx[m]] = bf16(feats[m] @ W + b) ----------------
__global__ void k_proj8(const float* __restrict__ feats, const float* __restrict__ W,
                        const float* __restrict__ bias, const int* __restrict__ idx,
                        unsigned short* __restrict__ xb, int M, int K) {
    __shared__ float lds[8 * 256];
    int m0 = blockIdx.x * 8;
    int rows = M - m0; if (rows > 8) rows = 8;
    for (int i = threadIdx.x; i < rows * K; i += 128) {
        int r = i / K, k = i - r * K;
        lds[r * K + k] = feats[(size_t)(m0 + r) * K + k];
    }
    __syncthreads();
    int o = threadIdx.x;  // 0..127 output col
    float bz = bias[o];
    float acc[8];
#pragma unroll
    for (int r = 0; r < 8; ++r) acc[r] = bz;
    for (int k = 0; k < K; ++k) {
        float wv = W[k * D + o];
#pragma unroll
        for (int r = 0; r < 8; ++r) acc[r] = fmaf(lds[r * K + k], wv, acc[r]);
    }
#pragma unroll
    for (int r = 0; r < 8; ++r) {
        if (r < rows) xb[(size_t)idx[m0 + r] * D + o] = f2bf(acc[r]);
    }
}

// ---------------- degree histogram ----------------
__global__ void k_deg(const int* __restrict__ ei, int* __restrict__ deg, int E) {
    int e = blockIdx.x * blockDim.x + threadIdx.x;
    if (e < E) atomicAdd(&deg[ei[E + e]], 1);
}

// ---------------- exclusive scan (3 kernels) ----------------
#define SCAN_B 256
__global__ void k_scan1(const int* __restrict__ deg, int* __restrict__ off,
                        int* __restrict__ bsum, int n) {
    __shared__ int lds[SCAN_B];
    int i = blockIdx.x * SCAN_B + threadIdx.x;
    int v = (i < n) ? deg[i] : 0;
    lds[threadIdx.x] = v; __syncthreads();
    for (int s = 1; s < SCAN_B; s <<= 1) {
        int t = (threadIdx.x >= s) ? lds[threadIdx.x - s] : 0;
        __syncthreads();
        lds[threadIdx.x] += t;
        __syncthreads();
    }
    if (i < n) off[i] = lds[threadIdx.x] - v;  // exclusive
    if (threadIdx.x == SCAN_B - 1) bsum[blockIdx.x] = lds[threadIdx.x];
}
__global__ void k_scan2(int* __restrict__ bsum, int nb) {
    __shared__ int lds[SCAN_B];
    int v = (threadIdx.x < nb) ? bsum[threadIdx.x] : 0;
    lds[threadIdx.x] = v; __syncthreads();
    for (int s = 1; s < SCAN_B; s <<= 1) {
        int t = (threadIdx.x >= s) ? lds[threadIdx.x - s] : 0;
        __syncthreads();
        lds[threadIdx.x] += t;
        __syncthreads();
    }
    if (threadIdx.x < nb) bsum[threadIdx.x] = lds[threadIdx.x] - v;
}
__global__ void k_scan3(int* __restrict__ off, const int* __restrict__ bsum,
                        int* __restrict__ cursor, int n) {
    int i = blockIdx.x * SCAN_B + threadIdx.x;
    if (i < n) {
        int o = off[i] + bsum[blockIdx.x];
        off[i] = o;
        cursor[i] = o;
    }
}

// ---------------- CSR fill: csr[p] = src | etype<<16 ----------------
__global__ void k_fill(const int* __restrict__ ei, const int* __restrict__ et,
                       int* __restrict__ cursor, unsigned* __restrict__ csr, int E) {
    int e = blockIdx.x * blockDim.x + threadIdx.x;
    if (e < E) {
        int d = ei[E + e];
        int p = atomicAdd(&cursor[d], 1);
        csr[p] = (unsigned)ei[e] | ((unsigned)et[e] << 16);
    }
}

// ---------------- aggregation: Zb[n, b*128+d] = bf16( sum_r comp[r,b]*mean[r,n,d] ) ----
// One node per wave. Weighted-sum form: z[b] = sum_e (comp[et,b]/cnt[et]) * x[src].
// Count pre-pass via ballot; weights held lane-r-wise, fetched per edge via readlane
// (scalar data-indexing, no branches). 8 register accumulators, no LDS, no barriers.
__global__ void k_agg(const unsigned short* __restrict__ xb, const int* __restrict__ off,
                      const int* __restrict__ deg, const unsigned* __restrict__ csr,
                      const float* __restrict__ comp, unsigned short* __restrict__ Zb, int Nn) {
    int w = threadIdx.x >> 6;
    int lane = threadIdx.x & 63;
    int n = blockIdx.x * 4 + w;
    if (n >= Nn) return;

    int start = off[n];
    int dg = deg[n];
    const unsigned* cp = csr + start;

    // ---- pass 1: per-relation counts (lane r holds cnt[r]) ----
    int myCnt = 0;
    for (int j0 = 0; j0 < dg; j0 += 64) {
        int m = dg - j0; if (m > 64) m = 64;
        unsigned myU = (lane < m) ? cp[j0 + lane] : 0xFFFFFFFFu;  // sentinel et=0xFFFF
        int etl = (int)(myU >> 16);
#pragma unroll
        for (int r = 0; r < R_REL; ++r) {
            unsigned long long mask = __ballot(etl == r);
            if (lane == r) myCnt += __popcll(mask);
        }
    }
    // ---- weights: lane r<10 holds w[b] = comp[r,b] * (cnt>0 ? 1/cnt : 1) ----
    float w0 = 0.f, w1 = 0.f, w2 = 0.f, w3 = 0.f;
    if (lane < R_REL) {
        float inv = (myCnt > 0) ? (1.f / (float)myCnt) : 1.f;
        float4 c4 = *(const float4*)&comp[lane * NBASE];
        w0 = c4.x * inv; w1 = c4.y * inv; w2 = c4.z * inv; w3 = c4.w * inv;
    }

    float z0x = 0.f, z0y = 0.f, z1x = 0.f, z1y = 0.f;
    float z2x = 0.f, z2y = 0.f, z3x = 0.f, z3y = 0.f;

    // ---- pass 2: weighted accumulate, 1-deep row prefetch ----
    for (int j0 = 0; j0 < dg; j0 += 64) {
        int m = dg - j0; if (m > 64) m = 64;
        unsigned myU = (lane < m) ? cp[j0 + lane] : 0u;
        unsigned u = (unsigned)__builtin_amdgcn_readlane((int)myU, 0);
        unsigned xv = ((const unsigned*)(xb + (size_t)(u & 0xFFFFu) * D))[lane];
        for (int jj = 0; jj < m; ++jj) {
            unsigned uc = u, xc = xv;
            if (jj + 1 < m) {   // prefetch next edge's row
                u = (unsigned)__builtin_amdgcn_readlane((int)myU, jj + 1);
                xv = ((const unsigned*)(xb + (size_t)(u & 0xFFFFu) * D))[lane];
            }
            int et = (int)(uc >> 16);   // wave-uniform (SGPR)
            float vx = __uint_as_float(xc << 16);
            float vy = __uint_as_float(xc & 0xFFFF0000u);
            float a0 = __uint_as_float((unsigned)__builtin_amdgcn_readlane((int)__float_as_uint(w0), et));
            float a1 = __uint_as_float((unsigned)__builtin_amdgcn_readlane((int)__float_as_uint(w1), et));
            float a2 = __uint_as_float((unsigned)__builtin_amdgcn_readlane((int)__float_as_uint(w2), et));
            float a3 = __uint_as_float((unsigned)__builtin_amdgcn_readlane((int)__float_as_uint(w3), et));
            z0x = fmaf(a0, vx, z0x); z0y = fmaf(a0, vy, z0y);
            z1x = fmaf(a1, vx, z1x); z1y = fmaf(a1, vy, z1y);
            z2x = fmaf(a2, vx, z2x); z2y = fmaf(a2, vy, z2y);
            z3x = fmaf(a3, vx, z3x); z3y = fmaf(a3, vy, z3y);
        }
    }

    unsigned short* zp = Zb + (size_t)n * 512 + lane * 2;
    *(unsigned*)(zp)       = (unsigned)f2bf(z0x) | ((unsigned)f2bf(z0y) << 16);
    *(unsigned*)(zp + 128) = (unsigned)f2bf(z1x) | ((unsigned)f2bf(z1y) << 16);
    *(unsigned*)(zp + 256) = (unsigned)f2bf(z2x) | ((unsigned)f2bf(z2y) << 16);
    *(unsigned*)(zp + 384) = (unsigned)f2bf(z3x) | ((unsigned)f2bf(z3y) << 16);
}

// ---------------- B panel transpose+cast: BT[n][k] = bf16([bases;root][k][n]) ----------
__global__ void k_bt(const float* __restrict__ bases, const float* __restrict__ root,
                     unsigned short* __restrict__ BT) {
    int i = blockIdx.x * 256 + threadIdx.x;       // over 128*640
    if (i >= 128 * 640) return;
    int n = i / 640, k = i - n * 640;
    float v = (k < 512) ? bases[(size_t)k * D + n] : root[(size_t)(k - 512) * D + n];
    BT[i] = f2bf(v);
}

// ---------------- MFMA layer GEMM: P = [Zb | xb] @ BT^T + bias ----------------
// M rows, K=640, N=128. BM=64, 256 threads = 4 waves, each wave 32x64.
// Double-buffered LDS, global->reg prefetch before MFMAs, ONE barrier per K-step.
// LDS rows padded to 80B (5 x 16B slots) -> <=2-way bank aliasing.
__global__ void k_gemm_mfma(const unsigned short* __restrict__ Zb,
                            const unsigned short* __restrict__ xb,
                            const unsigned short* __restrict__ BT,
                            const float* __restrict__ bias,
                            float* __restrict__ P, int M) {
    __shared__ unsigned short As[2][64 * 40];    // 10 KB
    __shared__ unsigned short Bs[2][128 * 40];   // 20.5 KB
    int t = threadIdx.x;
    int l = t & 63;
    int w = t >> 6;
    int wm = w & 1;               // 32-row half
    int wn = (w >> 1) * 64;       // 64-col half
    int m0 = blockIdx.x * 64;
    int lrow = l & 15;
    int kq = l >> 4;              // 0..3

    f32x4 acc[2][4];
#pragma unroll
    for (int s = 0; s < 2; ++s)
#pragma unroll
        for (int ct = 0; ct < 4; ++ct) acc[s][ct] = (f32x4){0.f, 0.f, 0.f, 0.f};

    // staging assignments: A 64x32 tile, 8 bf16 (16B) per thread
    int arow = t >> 2, ako = (t & 3) * 8;
    // B 128x32 tile, 16 bf16 (32B) per thread
    int brow = t >> 1, bko = (t & 1) * 16;
    int arg = m0 + arow; if (arg >= M) arg = M - 1;

    uint4 aR, bR0, bR1;
    auto gload = [&](int k0) {
        const unsigned short* asrc = (k0 < 512)
            ? &Zb[(size_t)arg * 512 + k0 + ako]
            : &xb[(size_t)arg * D + (k0 - 512) + ako];
        aR = *(const uint4*)asrc;
        const unsigned short* bsrc = &BT[(size_t)brow * 640 + k0 + bko];
        bR0 = *(const uint4*)bsrc;
        bR1 = *(const uint4*)(bsrc + 8);
    };
    auto sstore = [&](int p) {
        *(uint4*)&As[p][arow * 40 + ako] = aR;
        *(uint4*)&Bs[p][brow * 40 + bko] = bR0;
        *(uint4*)&Bs[p][brow * 40 + bko + 8] = bR1;
    };

    gload(0);
    sstore(0);
    int p = 0;
    for (int k0 = 0; k0 < 640; k0 += 32) {
        __syncthreads();                       // buf[p] ready for all waves
        if (k0 + 32 < 640) gload(k0 + 32);     // issue next-tile loads (overlap MFMA)
        short8 a0 = *(const short8*)&As[p][(wm * 32 + lrow) * 40 + kq * 8];
        short8 a1 = *(const short8*)&As[p][(wm * 32 + 16 + lrow) * 40 + kq * 8];
#pragma unroll
        for (int ct = 0; ct < 4; ++ct) {
            short8 b = *(const short8*)&Bs[p][(wn + ct * 16 + lrow) * 40 + kq * 8];
            acc[0][ct] = __builtin_amdgcn_mfma_f32_16x16x32_bf16(a0, b, acc[0][ct], 0, 0, 0);
            acc[1][ct] = __builtin_amdgcn_mfma_f32_16x16x32_bf16(a1, b, acc[1][ct], 0, 0, 0);
        }
        if (k0 + 32 < 640) { sstore(p ^ 1); p ^= 1; }
    }

    int r0 = m0 + wm * 32 + kq * 4;
#pragma unroll
    for (int sub = 0; sub < 2; ++sub) {
#pragma unroll
        for (int ct = 0; ct < 4; ++ct) {
            int col = wn + ct * 16 + lrow;
            float bv = bias[col];
#pragma unroll
            for (int r = 0; r < 4; ++r) {
                int rg = r0 + sub * 16 + r;
                if (rg < M) P[(size_t)rg * D + col] = acc[sub][ct][r] + bv;
            }
        }
    }
}

// ---------------- LayerNorm + ReLU -> bf16 ----------------
__global__ void k_lnrelu(const float* __restrict__ P, const float* __restrict__ g,
                         const float* __restrict__ b, unsigned short* __restrict__ hb, int Nn) {
    int w = threadIdx.x >> 6, lane = threadIdx.x & 63;
    int n = blockIdx.x * 4 + w;
    if (n >= Nn) return;
    float2 v = *(const float2*)&P[(size_t)n * D + lane * 2];
    float s = v.x + v.y;
#pragma unroll
    for (int o = 1; o < 64; o <<= 1) s += __shfl_xor(s, o, 64);
    float m = s * (1.f / 128.f);
    float dx = v.x - m, dy = v.y - m;
    float vs = dx * dx + dy * dy;
#pragma unroll
    for (int o = 1; o < 64; o <<= 1) vs += __shfl_xor(vs, o, 64);
    float inv = rsqrtf(vs * (1.f / 128.f) + LN_EPS);
    float2 gg = *(const float2*)&g[lane * 2];
    float2 bb = *(const float2*)&b[lane * 2];
    float ox = fmaxf(dx * inv * gg.x + bb.x, 0.f);
    float oy = fmaxf(dy * inv * gg.y + bb.y, 0.f);
    unsigned o2 = (unsigned)f2bf(ox) | ((unsigned)f2bf(oy) << 16);
    *(unsigned*)&hb[(size_t)n * D + lane * 2] = o2;
}

// ---------------- final: gather + LN + relu(h@Wc1+bc1) @ Wc2 + bc2 ----------------
__global__ void k_final(const float* __restrict__ P2, const int* __restrict__ nidx,
                        const float* __restrict__ g, const float* __restrict__ b,
                        const float* __restrict__ Wc1, const float* __restrict__ bc1,
                        const float* __restrict__ Wc2, const float* __restrict__ bc2,
                        float* __restrict__ out, int M) {
    __shared__ float ln[D];
    __shared__ float t[D];
    __shared__ float red[2];
    int i = blockIdx.x;
    if (i >= M) return;
    int d = threadIdx.x;
    int n = nidx[i];
    float v = P2[(size_t)n * D + d];
    float s = v;
#pragma unroll
    for (int o = 1; o < 64; o <<= 1) s += __shfl_xor(s, o, 64);
    if ((d & 63) == 0) red[d >> 6] = s;
    __syncthreads();
    float m = (red[0] + red[1]) * (1.f / 128.f);
    __syncthreads();
    float dv = v - m;
    float vs = dv * dv;
#pragma unroll
    for (int o = 1; o < 64; o <<= 1) vs += __shfl_xor(vs, o, 64);
    if ((d & 63) == 0) red[d >> 6] = vs;
    __syncthreads();
    float inv = rsqrtf((red[0] + red[1]) * (1.f / 128.f) + LN_EPS);
    ln[d] = dv * inv * g[d] + b[d];
    __syncthreads();
    float a = bc1[d];
    for (int k = 0; k < D; ++k) a = fmaf(ln[k], Wc1[k * D + d], a);
    t[d] = fmaxf(a, 0.f);
    __syncthreads();
    if (d < NC) {
        float o2 = bc2[d];
        for (int k = 0; k < D; ++k) o2 = fmaf(t[k], Wc2[k * NC + d], o2);
        out[(size_t)i * NC + d] = o2;
    }
}

extern "C" void kernel_launch(void* const* d_in, const int* in_sizes, int n_in,
                              void* d_out, int out_size, void* d_ws, size_t ws_size,
                              hipStream_t stream) {
    const int*   edge_index   = (const int*)d_in[0];
    const int*   edge_type    = (const int*)d_in[1];
    const int*   node_indices = (const int*)d_in[2];
    const float* file_feats   = (const float*)d_in[3];
    const int*   file_idx     = (const int*)d_in[4];
    const float* domain_feats = (const float*)d_in[5];
    const int*   domain_idx   = (const int*)d_in[6];
    const float* ip_feats     = (const float*)d_in[7];
    const int*   ip_idx       = (const int*)d_in[8];
    const float* fallback     = (const float*)d_in[9];
    const float* Wf = (const float*)d_in[10]; const float* bf = (const float*)d_in[11];
    const float* Wd = (const float*)d_in[12]; const float* bd = (const float*)d_in[13];
    const float* Wi = (const float*)d_in[14]; const float* bi = (const float*)d_in[15];
    const float* comp1 = (const float*)d_in[16]; const float* bases1 = (const float*)d_in[17];
    const float* root1 = (const float*)d_in[18]; const float* bias1 = (const float*)d_in[19];
    const float* comp2 = (const float*)d_in[20]; const float* bases2 = (const float*)d_in[21];
    const float* root2 = (const float*)d_in[22]; const float* bias2 = (const float*)d_in[23];
    const float* ln1g = (const float*)d_in[24]; const float* ln1b = (const float*)d_in[25];
    const float* ln2g = (const float*)d_in[26]; const float* ln2b = (const float*)d_in[27];
    const float* Wc1 = (const float*)d_in[28]; const float* bc1 = (const float*)d_in[29];
    const float* Wc2 = (const float*)d_in[30]; const float* bc2 = (const float*)d_in[31];

    const int E  = in_sizes[1];
    const int Nn = in_sizes[9] / D;
    const int Mf = in_sizes[4], Kf = in_sizes[3] / Mf;
    const int Md = in_sizes[6], Kd = in_sizes[5] / Md;
    const int Mi = in_sizes[8], Ki = in_sizes[7] / Mi;
    const int Msel = in_sizes[2];

    char* w = (char*)d_ws;
    auto alloc = [&](size_t bytes) {
        char* p = w;
        w += (bytes + 255) & ~(size_t)255;
        return p;
    };
    unsigned short* xb  = (unsigned short*)alloc((size_t)Nn * D * 2);   // 12.8 MB
    unsigned short* h1b = (unsigned short*)alloc((size_t)Nn * D * 2);   // 12.8 MB
    float*          P   = (float*)alloc((size_t)Nn * D * 4);            // 25.6 MB
    unsigned short* Zb  = (unsigned short*)alloc((size_t)Nn * 512 * 2); // 51.2 MB
    unsigned short* BT1 = (unsigned short*)alloc((size_t)128 * 640 * 2);
    unsigned short* BT2 = (unsigned short*)alloc((size_t)128 * 640 * 2);
    int* deg    = (int*)alloc((size_t)Nn * 4);
    int* off    = (int*)alloc((size_t)Nn * 4);
    int* cursor = (int*)alloc((size_t)Nn * 4);
    int* bsum   = (int*)alloc(1024);
    unsigned* csr = (unsigned*)alloc((size_t)E * 4);                    // 3.2 MB

    hipMemsetAsync(deg, 0, (size_t)Nn * 4, stream);

    // node features (bf16)
    int n4 = Nn * D / 4;
    k_copy_bf<<<(n4 + 255) / 256, 256, 0, stream>>>((const float4*)fallback, (uint2*)xb, n4);
    k_proj8<<<(Mf + 7) / 8, 128, 0, stream>>>(file_feats, Wf, bf, file_idx, xb, Mf, Kf);
    k_proj8<<<(Md + 7) / 8, 128, 0, stream>>>(domain_feats, Wd, bd, domain_idx, xb, Md, Kd);
    k_proj8<<<(Mi + 7) / 8, 128, 0, stream>>>(ip_feats, Wi, bi, ip_idx, xb, Mi, Ki);

    // B panels (bf16, transposed)
    int nbt = (128 * 640 + 255) / 256;
    k_bt<<<nbt, 256, 0, stream>>>(bases1, root1, BT1);
    k_bt<<<nbt, 256, 0, stream>>>(bases2, root2, BT2);

    // CSR by dst (shared by both layers)
    k_deg<<<(E + 255) / 256, 256, 0, stream>>>(edge_index, deg, E);
    int nb = (Nn + SCAN_B - 1) / SCAN_B;
    k_scan1<<<nb, SCAN_B, 0, stream>>>(deg, off, bsum, Nn);
    k_scan2<<<1, SCAN_B, 0, stream>>>(bsum, nb);
    k_scan3<<<nb, SCAN_B, 0, stream>>>(off, bsum, cursor, Nn);
    k_fill<<<(E + 255) / 256, 256, 0, stream>>>(edge_index, edge_type, cursor, csr, E);

    int gemmGrid = (Nn + 63) / 64;

    // layer 1
    k_agg<<<(Nn + 3) / 4, 256, 0, stream>>>(xb, off, deg, csr, comp1, Zb, Nn);
    k_gemm_mfma<<<gemmGrid, 256, 0, stream>>>(Zb, xb, BT1, bias1, P, Nn);
    k_lnrelu<<<(Nn + 3) / 4, 256, 0, stream>>>(P, ln1g, ln1b, h1b, Nn);

    // layer 2
    k_agg<<<(Nn + 3) / 4, 256, 0, stream>>>(h1b, off, deg, csr, comp2, Zb, Nn);
    k_gemm_mfma<<<gemmGrid, 256, 0, stream>>>(Zb, h1b, BT2, bias2, P, Nn);

    // head
    k_final<<<Msel, 128, 0, stream>>>(P, node_indices, ln2g, ln2b, Wc1, bc1, Wc2, bc2,
                                      (float*)d_out, Msel);
}

// Round 9
// 546.536 us; speedup vs baseline: 1.0532x; 1.0007x over previous
//
#include <hip/hip_runtime.h>

#define D 128
#define R_REL 10
#define NBASE 4
#define NC 12
#define LN_EPS 1e-5f

typedef __attribute__((ext_vector_type(8))) short short8;
typedef __attribute__((ext_vector_type(4))) float f32x4;

static __device__ __forceinline__ unsigned short f2bf(float f) {
    unsigned u = __float_as_uint(f);
    unsigned r = (u + 0x7FFFu + ((u >> 16) & 1u)) >> 16;   // RNE
    return (unsigned short)r;
}

// ---------------- fallback f32 -> xb bf16 ----------------
__global__ void k_copy_bf(const float4* __restrict__ src, uint2* __restrict__ dst, int n4) {
    int i = blockIdx.x * blockDim.x + threadIdx.x;
    if (i < n4) {
        float4 v = src[i];
        uint2 o;
        o.x = (unsigned)f2bf(v.x) | ((unsigned)f2bf(v.y) << 16);
        o.y = (unsigned)f2bf(v.z) | ((unsigned)f2bf(v.w) << 16);
        dst[i] = o;
    }
}

// ---------------- typed projection: xb[idx[m]] = bf16(feats[m] @ W + b) ----------------
__global__ void k_proj8(const float* __restrict__ feats, const float* __restrict__ W,
                        const float* __restrict__ bias, const int* __restrict__ idx,
                        unsigned short* __restrict__ xb, int M, int K) {
    __shared__ float lds[8 * 256];
    int m0 = blockIdx.x * 8;
    int rows = M - m0; if (rows > 8) rows = 8;
    for (int i = threadIdx.x; i < rows * K; i += 128) {
        int r = i / K, k = i - r * K;
        lds[r * K + k] = feats[(size_t)(m0 + r) * K + k];
    }
    __syncthreads();
    int o = threadIdx.x;  // 0..127 output col
    float bz = bias[o];
    float acc[8];
#pragma unroll
    for (int r = 0; r < 8; ++r) acc[r] = bz;
    for (int k = 0; k < K; ++k) {
        float wv = W[k * D + o];
#pragma unroll
        for (int r = 0; r < 8; ++r) acc[r] = fmaf(lds[r * K + k], wv, acc[r]);
    }
#pragma unroll
    for (int r = 0; r < 8; ++r) {
        if (r < rows) xb[(size_t)idx[m0 + r] * D + o] = f2bf(acc[r]);
    }
}

// ---------------- degree + per-(node,relation) count histogram ----------------
__global__ void k_degcnt(const int* __restrict__ ei, const int* __restrict__ et,
                         int* __restrict__ deg, int* __restrict__ cntNR, int E) {
    int e = blockIdx.x * blockDim.x + threadIdx.x;
    if (e < E) {
        int d = ei[E + e];
        atomicAdd(&deg[d], 1);
        atomicAdd(&cntNR[d * 16 + et[e]], 1);
    }
}

// ---------------- exclusive scan (3 kernels) ----------------
#define SCAN_B 256
__global__ void k_scan1(const int* __restrict__ deg, int* __restrict__ off,
                        int* __restrict__ bsum, int n) {
    __shared__ int lds[SCAN_B];
    int i = blockIdx.x * SCAN_B + threadIdx.x;
    int v = (i < n) ? deg[i] : 0;
    lds[threadIdx.x] = v; __syncthreads();
    for (int s = 1; s < SCAN_B; s <<= 1) {
        int t = (threadIdx.x >= s) ? lds[threadIdx.x - s] : 0;
        __syncthreads();
        lds[threadIdx.x] += t;
        __syncthreads();
    }
    if (i < n) off[i] = lds[threadIdx.x] - v;  // exclusive
    if (threadIdx.x == SCAN_B - 1) bsum[blockIdx.x] = lds[threadIdx.x];
}
__global__ void k_scan2(int* __restrict__ bsum, int nb) {
    __shared__ int lds[SCAN_B];
    int v = (threadIdx.x < nb) ? bsum[threadIdx.x] : 0;
    lds[threadIdx.x] = v; __syncthreads();
    for (int s = 1; s < SCAN_B; s <<= 1) {
        int t = (threadIdx.x >= s) ? lds[threadIdx.x - s] : 0;
        __syncthreads();
        lds[threadIdx.x] += t;
        __syncthreads();
    }
    if (threadIdx.x < nb) bsum[threadIdx.x] = lds[threadIdx.x] - v;
}
__global__ void k_scan3(int* __restrict__ off, const int* __restrict__ bsum,
                        int* __restrict__ cursor, int n) {
    int i = blockIdx.x * SCAN_B + threadIdx.x;
    if (i < n) {
        int o = off[i] + bsum[blockIdx.x];
        off[i] = o;
        cursor[i] = o;
    }
}

// ---------------- CSR fill: csr[p] = src | etype<<16 ----------------
__global__ void k_fill(const int* __restrict__ ei, const int* __restrict__ et,
                       int* __restrict__ cursor, unsigned* __restrict__ csr, int E) {
    int e = blockIdx.x * blockDim.x + threadIdx.x;
    if (e < E) {
        int d = ei[E + e];
        int p = atomicAdd(&cursor[d], 1);
        csr[p] = (unsigned)ei[e] | ((unsigned)et[e] << 16);
    }
}

// ---------------- aggregation: Zb[n, b*128+d] = bf16( sum_r comp[r,b]*mean[r,n,d] ) ----
// One node per wave. Weighted-sum form: z[b] = sum_e (comp[et,b]/cnt[et]) * x[src].
// Counts precomputed in CSR build (cntNR). Weights lane-r-wise, fetched per edge via
// readlane (scalar data-indexing, no branches). 4-edge groups, 1-group-deep load
// pipeline (4 outstanding row loads). Sentinel-padded tails (et=63 -> weight 0).
__global__ void k_agg(const unsigned short* __restrict__ xb, const int* __restrict__ off,
                      const int* __restrict__ deg, const int* __restrict__ cntNR,
                      const unsigned* __restrict__ csr,
                      const float* __restrict__ comp, unsigned short* __restrict__ Zb, int Nn) {
    int w = threadIdx.x >> 6;
    int lane = threadIdx.x & 63;
    int n = blockIdx.x * 4 + w;
    if (n >= Nn) return;

    int start = off[n];
    int dg = deg[n];
    const unsigned* cp = csr + start;

    // lane r<10 holds w[b] = comp[r,b] * (cnt>0 ? 1/cnt : 1); lanes 10..63 hold 0
    float w0 = 0.f, w1 = 0.f, w2 = 0.f, w3 = 0.f;
    if (lane < R_REL) {
        int c = cntNR[n * 16 + lane];
        float inv = (c > 0) ? (1.f / (float)c) : 1.f;
        float4 c4 = *(const float4*)&comp[lane * NBASE];
        w0 = c4.x * inv; w1 = c4.y * inv; w2 = c4.z * inv; w3 = c4.w * inv;
    }

    float z0x = 0.f, z0y = 0.f, z1x = 0.f, z1y = 0.f;
    float z2x = 0.f, z2y = 0.f, z3x = 0.f, z3y = 0.f;

#define RL(i)  (unsigned)__builtin_amdgcn_readlane((int)myU, (i))
#define ROW(u) (((const unsigned*)(xb + (size_t)((u) & 0xFFFFu) * D))[lane])
#define PROC(uu, xx) { \
    int et = (int)((uu) >> 16); \
    float vx = __uint_as_float((xx) << 16); \
    float vy = __uint_as_float((xx) & 0xFFFF0000u); \
    float a0 = __uint_as_float((unsigned)__builtin_amdgcn_readlane((int)__float_as_uint(w0), et)); \
    float a1 = __uint_as_float((unsigned)__builtin_amdgcn_readlane((int)__float_as_uint(w1), et)); \
    float a2 = __uint_as_float((unsigned)__builtin_amdgcn_readlane((int)__float_as_uint(w2), et)); \
    float a3 = __uint_as_float((unsigned)__builtin_amdgcn_readlane((int)__float_as_uint(w3), et)); \
    z0x = fmaf(a0, vx, z0x); z0y = fmaf(a0, vy, z0y); \
    z1x = fmaf(a1, vx, z1x); z1y = fmaf(a1, vy, z1y); \
    z2x = fmaf(a2, vx, z2x); z2y = fmaf(a2, vy, z2y); \
    z3x = fmaf(a3, vx, z3x); z3y = fmaf(a3, vy, z3y); }

    for (int j0 = 0; j0 < dg; j0 += 64) {
        int m = dg - j0; if (m > 64) m = 64;
        // sentinel: src=0, et=63 -> zero weight, harmless L2-hot load
        unsigned myU = (lane < m) ? cp[j0 + lane] : 0x003F0000u;
        int mm = (m + 3) & ~3;

        unsigned ua0 = RL(0), ua1 = RL(1), ua2 = RL(2), ua3 = RL(3);
        unsigned xa0 = ROW(ua0), xa1 = ROW(ua1), xa2 = ROW(ua2), xa3 = ROW(ua3);

        for (int jj = 0; jj < mm; jj += 4) {
            unsigned ub0, ub1, ub2, ub3, xv0, xv1, xv2, xv3;
            bool more = (jj + 4) < mm;          // wave-uniform
            if (more) {                          // issue next group's 4 loads
                ub0 = RL(jj + 4); ub1 = RL(jj + 5); ub2 = RL(jj + 6); ub3 = RL(jj + 7);
                xv0 = ROW(ub0); xv1 = ROW(ub1); xv2 = ROW(ub2); xv3 = ROW(ub3);
            }
            PROC(ua0, xa0); PROC(ua1, xa1); PROC(ua2, xa2); PROC(ua3, xa3);
            if (more) {
                ua0 = ub0; ua1 = ub1; ua2 = ub2; ua3 = ub3;
                xa0 = xv0; xa1 = xv1; xa2 = xv2; xa3 = xv3;
            }
        }
    }
#undef RL
#undef ROW
#undef PROC

    unsigned short* zp = Zb + (size_t)n * 512 + lane * 2;
    *(unsigned*)(zp)       = (unsigned)f2bf(z0x) | ((unsigned)f2bf(z0y) << 16);
    *(unsigned*)(zp + 128) = (unsigned)f2bf(z1x) | ((unsigned)f2bf(z1y) << 16);
    *(unsigned*)(zp + 256) = (unsigned)f2bf(z2x) | ((unsigned)f2bf(z2y) << 16);
    *(unsigned*)(zp + 384) = (unsigned)f2bf(z3x) | ((unsigned)f2bf(z3y) << 16);
}

// ---------------- B panel transpose+cast: BT[n][k] = bf16([bases;root][k][n]) ----------
__global__ void k_bt(const float* __restrict__ bases, const float* __restrict__ root,
                     unsigned short* __restrict__ BT) {
    int i = blockIdx.x * 256 + threadIdx.x;       // over 128*640
    if (i >= 128 * 640) return;
    int n = i / 640, k = i - n * 640;
    float v = (k < 512) ? bases[(size_t)k * D + n] : root[(size_t)(k - 512) * D + n];
    BT[i] = f2bf(v);
}

// ---------------- MFMA layer GEMM: P = [Zb | xb] @ BT^T + bias ----------------
// M rows, K=640, N=128. BM=64, 256 threads = 4 waves, each wave 32x64.
// Double-buffered LDS, global->reg prefetch before MFMAs, ONE barrier per K-step.
// LDS rows padded to 80B (5 x 16B slots) -> <=2-way bank aliasing.
__global__ void k_gemm_mfma(const unsigned short* __restrict__ Zb,
                            const unsigned short* __restrict__ xb,
                            const unsigned short* __restrict__ BT,
                            const float* __restrict__ bias,
                            float* __restrict__ P, int M) {
    __shared__ unsigned short As[2][64 * 40];    // 10 KB
    __shared__ unsigned short Bs[2][128 * 40];   // 20.5 KB
    int t = threadIdx.x;
    int l = t & 63;
    int w = t >> 6;
    int wm = w & 1;               // 32-row half
    int wn = (w >> 1) * 64;       // 64-col half
    int m0 = blockIdx.x * 64;
    int lrow = l & 15;
    int kq = l >> 4;              // 0..3

    f32x4 acc[2][4];
#pragma unroll
    for (int s = 0; s < 2; ++s)
#pragma unroll
        for (int ct = 0; ct < 4; ++ct) acc[s][ct] = (f32x4){0.f, 0.f, 0.f, 0.f};

    // staging assignments: A 64x32 tile, 8 bf16 (16B) per thread
    int arow = t >> 2, ako = (t & 3) * 8;
    // B 128x32 tile, 16 bf16 (32B) per thread
    int brow = t >> 1, bko = (t & 1) * 16;
    int arg = m0 + arow; if (arg >= M) arg = M - 1;

    uint4 aR, bR0, bR1;
    auto gload = [&](int k0) {
        const unsigned short* asrc = (k0 < 512)
            ? &Zb[(size_t)arg * 512 + k0 + ako]
            : &xb[(size_t)arg * D + (k0 - 512) + ako];
        aR = *(const uint4*)asrc;
        const unsigned short* bsrc = &BT[(size_t)brow * 640 + k0 + bko];
        bR0 = *(const uint4*)bsrc;
        bR1 = *(const uint4*)(bsrc + 8);
    };
    auto sstore = [&](int p) {
        *(uint4*)&As[p][arow * 40 + ako] = aR;
        *(uint4*)&Bs[p][brow * 40 + bko] = bR0;
        *(uint4*)&Bs[p][brow * 40 + bko + 8] = bR1;
    };

    gload(0);
    sstore(0);
    int p = 0;
    for (int k0 = 0; k0 < 640; k0 += 32) {
        __syncthreads();                       // buf[p] ready for all waves
        if (k0 + 32 < 640) gload(k0 + 32);     // issue next-tile loads (overlap MFMA)
        short8 a0 = *(const short8*)&As[p][(wm * 32 + lrow) * 40 + kq * 8];
        short8 a1 = *(const short8*)&As[p][(wm * 32 + 16 + lrow) * 40 + kq * 8];
#pragma unroll
        for (int ct = 0; ct < 4; ++ct) {
            short8 b = *(const short8*)&Bs[p][(wn + ct * 16 + lrow) * 40 + kq * 8];
            acc[0][ct] = __builtin_amdgcn_mfma_f32_16x16x32_bf16(a0, b, acc[0][ct], 0, 0, 0);
            acc[1][ct] = __builtin_amdgcn_mfma_f32_16x16x32_bf16(a1, b, acc[1][ct], 0, 0, 0);
        }
        if (k0 + 32 < 640) { sstore(p ^ 1); p ^= 1; }
    }

    int r0 = m0 + wm * 32 + kq * 4;
#pragma unroll
    for (int sub = 0; sub < 2; ++sub) {
#pragma unroll
        for (int ct = 0; ct < 4; ++ct) {
            int col = wn + ct * 16 + lrow;
            float bv = bias[col];
#pragma unroll
            for (int r = 0; r < 4; ++r) {
                int rg = r0 + sub * 16 + r;
                if (rg < M) P[(size_t)rg * D + col] = acc[sub][ct][r] + bv;
            }
        }
    }
}

// ---------------- LayerNorm + ReLU -> bf16 ----------------
__global__ void k_lnrelu(const float* __restrict__ P, const float* __restrict__ g,
                         const float* __restrict__ b, unsigned short* __restrict__ hb, int Nn) {
    int w = threadIdx.x >> 6, lane = threadIdx.x & 63;
    int n = blockIdx.x * 4 + w;
    if (n >= Nn) return;
    float2 v = *(const float2*)&P[(size_t)n * D + lane * 2];
    float s = v.x + v.y;
#pragma unroll
    for (int o = 1; o < 64; o <<= 1) s += __shfl_xor(s, o, 64);
    float m = s * (1.f / 128.f);
    float dx = v.x - m, dy = v.y - m;
    float vs = dx * dx + dy * dy;
#pragma unroll
    for (int o = 1; o < 64; o <<= 1) vs += __shfl_xor(vs, o, 64);
    float inv = rsqrtf(vs * (1.f / 128.f) + LN_EPS);
    float2 gg = *(const float2*)&g[lane * 2];
    float2 bb = *(const float2*)&b[lane * 2];
    float ox = fmaxf(dx * inv * gg.x + bb.x, 0.f);
    float oy = fmaxf(dy * inv * gg.y + bb.y, 0.f);
    unsigned o2 = (unsigned)f2bf(ox) | ((unsigned)f2bf(oy) << 16);
    *(unsigned*)&hb[(size_t)n * D + lane * 2] = o2;
}

// ---------------- final: gather + LN + relu(h@Wc1+bc1) @ Wc2 + bc2 ----------------
__global__ void k_final(const float* __restrict__ P2, const int* __restrict__ nidx,
                        const float* __restrict__ g, const float* __restrict__ b,
                        const float* __restrict__ Wc1, const float* __restrict__ bc1,
                        const float* __restrict__ Wc2, const float* __restrict__ bc2,
                        float* __restrict__ out, int M) {
    __shared__ float ln[D];
    __shared__ float t[D];
    __shared__ float red[2];
    int i = blockIdx.x;
    if (i >= M) return;
    int d = threadIdx.x;
    int n = nidx[i];
    float v = P2[(size_t)n * D + d];
    float s = v;
#pragma unroll
    for (int o = 1; o < 64; o <<= 1) s += __shfl_xor(s, o, 64);
    if ((d & 63) == 0) red[d >> 6] = s;
    __syncthreads();
    float m = (red[0] + red[1]) * (1.f / 128.f);
    __syncthreads();
    float dv = v - m;
    float vs = dv * dv;
#pragma unroll
    for (int o = 1; o < 64; o <<= 1) vs += __shfl_xor(vs, o, 64);
    if ((d & 63) == 0) red[d >> 6] = vs;
    __syncthreads();
    float inv = rsqrtf((red[0] + red[1]) * (1.f / 128.f) + LN_EPS);
    ln[d] = dv * inv * g[d] + b[d];
    __syncthreads();
    float a = bc1[d];
    for (int k = 0; k < D; ++k) a = fmaf(ln[k], Wc1[k * D + d], a);
    t[d] = fmaxf(a, 0.f);
    __syncthreads();
    if (d < NC) {
        float o2 = bc2[d];
        for (int k = 0; k < D; ++k) o2 = fmaf(t[k], Wc2[k * NC + d], o2);
        out[(size_t)i * NC + d] = o2;
    }
}

extern "C" void kernel_launch(void* const* d_in, const int* in_sizes, int n_in,
                              void* d_out, int out_size, void* d_ws, size_t ws_size,
                              hipStream_t stream) {
    const int*   edge_index   = (const int*)d_in[0];
    const int*   edge_type    = (const int*)d_in[1];
    const int*   node_indices = (const int*)d_in[2];
    const float* file_feats   = (const float*)d_in[3];
    const int*   file_idx     = (const int*)d_in[4];
    const float* domain_feats = (const float*)d_in[5];
    const int*   domain_idx   = (const int*)d_in[6];
    const float* ip_feats     = (const float*)d_in[7];
    const int*   ip_idx       = (const int*)d_in[8];
    const float* fallback     = (const float*)d_in[9];
    const float* Wf = (const float*)d_in[10]; const float* bf = (const float*)d_in[11];
    const float* Wd = (const float*)d_in[12]; const float* bd = (const float*)d_in[13];
    const float* Wi = (const float*)d_in[14]; const float* bi = (const float*)d_in[15];
    const float* comp1 = (const float*)d_in[16]; const float* bases1 = (const float*)d_in[17];
    const float* root1 = (const float*)d_in[18]; const float* bias1 = (const float*)d_in[19];
    const float* comp2 = (const float*)d_in[20]; const float* bases2 = (const float*)d_in[21];
    const float* root2 = (const float*)d_in[22]; const float* bias2 = (const float*)d_in[23];
    const float* ln1g = (const float*)d_in[24]; const float* ln1b = (const float*)d_in[25];
    const float* ln2g = (const float*)d_in[26]; const float* ln2b = (const float*)d_in[27];
    const float* Wc1 = (const float*)d_in[28]; const float* bc1 = (const float*)d_in[29];
    const float* Wc2 = (const float*)d_in[30]; const float* bc2 = (const float*)d_in[31];

    const int E  = in_sizes[1];
    const int Nn = in_sizes[9] / D;
    const int Mf = in_sizes[4], Kf = in_sizes[3] / Mf;
    const int Md = in_sizes[6], Kd = in_sizes[5] / Md;
    const int Mi = in_sizes[8], Ki = in_sizes[7] / Mi;
    const int Msel = in_sizes[2];

    char* w = (char*)d_ws;
    auto alloc = [&](size_t bytes) {
        char* p = w;
        w += (bytes + 255) & ~(size_t)255;
        return p;
    };
    unsigned short* xb  = (unsigned short*)alloc((size_t)Nn * D * 2);   // 12.8 MB
    unsigned short* h1b = (unsigned short*)alloc((size_t)Nn * D * 2);   // 12.8 MB
    float*          P   = (float*)alloc((size_t)Nn * D * 4);            // 25.6 MB
    unsigned short* Zb  = (unsigned short*)alloc((size_t)Nn * 512 * 2); // 51.2 MB
    unsigned short* BT1 = (unsigned short*)alloc((size_t)128 * 640 * 2);
    unsigned short* BT2 = (unsigned short*)alloc((size_t)128 * 640 * 2);
    int* deg    = (int*)alloc((size_t)Nn * 4);
    int* cntNR  = (int*)alloc((size_t)Nn * 16 * 4);                     // 3.2 MB
    int* off    = (int*)alloc((size_t)Nn * 4);
    int* cursor = (int*)alloc((size_t)Nn * 4);
    int* bsum   = (int*)alloc(1024);
    unsigned* csr = (unsigned*)alloc((size_t)E * 4);                    // 3.2 MB

    hipMemsetAsync(deg, 0, (size_t)Nn * 4, stream);
    hipMemsetAsync(cntNR, 0, (size_t)Nn * 16 * 4, stream);

    // node features (bf16)
    int n4 = Nn * D / 4;
    k_copy_bf<<<(n4 + 255) / 256, 256, 0, stream>>>((const float4*)fallback, (uint2*)xb, n4);
    k_proj8<<<(Mf + 7) / 8, 128, 0, stream>>>(file_feats, Wf, bf, file_idx, xb, Mf, Kf);
    k_proj8<<<(Md + 7) / 8, 128, 0, stream>>>(domain_feats, Wd, bd, domain_idx, xb, Md, Kd);
    k_proj8<<<(Mi + 7) / 8, 128, 0, stream>>>(ip_feats, Wi, bi, ip_idx, xb, Mi, Ki);

    // B panels (bf16, transposed)
    int nbt = (128 * 640 + 255) / 256;
    k_bt<<<nbt, 256, 0, stream>>>(bases1, root1, BT1);
    k_bt<<<nbt, 256, 0, stream>>>(bases2, root2, BT2);

    // CSR by dst (shared by both layers); cntNR shared by both k_agg dispatches
    k_degcnt<<<(E + 255) / 256, 256, 0, stream>>>(edge_index, edge_type, deg, cntNR, E);
    int nb = (Nn + SCAN_B - 1) / SCAN_B;
    k_scan1<<<nb, SCAN_B, 0, stream>>>(deg, off, bsum, Nn);
    k_scan2<<<1, SCAN_B, 0, stream>>>(bsum, nb);
    k_scan3<<<nb, SCAN_B, 0, stream>>>(off, bsum, cursor, Nn);
    k_fill<<<(E + 255) / 256, 256, 0, stream>>>(edge_index, edge_type, cursor, csr, E);

    int gemmGrid = (Nn + 63) / 64;

    // layer 1
    k_agg<<<(Nn + 3) / 4, 256, 0, stream>>>(xb, off, deg, cntNR, csr, comp1, Zb, Nn);
    k_gemm_mfma<<<gemmGrid, 256, 0, stream>>>(Zb, xb, BT1, bias1, P, Nn);
    k_lnrelu<<<(Nn + 3) / 4, 256, 0, stream>>>(P, ln1g, ln1b, h1b, Nn);

    // layer 2
    k_agg<<<(Nn + 3) / 4, 256, 0, stream>>>(h1b, off, deg, cntNR, csr, comp2, Zb, Nn);
    k_gemm_mfma<<<gemmGrid, 256, 0, stream>>>(Zb, h1b, BT2, bias2, P, Nn);

    // head
    k_final<<<Msel, 128, 0, stream>>>(P, node_indices, ln2g, ln2b, Wc1, bc1, Wc2, bc2,
                                      (float*)d_out, Msel);
}

// Round 11
// 524.781 us; speedup vs baseline: 1.0968x; 1.0415x over previous
//
#include <hip/hip_runtime.h>

#define D 128
#define R_REL 10
#define NBASE 4
#define NC 12
#define LN_EPS 1e-5f

typedef __attribute__((ext_vector_type(8))) short short8;
typedef __attribute__((ext_vector_type(4))) float f32x4;

static __device__ __forceinline__ unsigned short f2bf(float f) {
    unsigned u = __float_as_uint(f);
    unsigned r = (u + 0x7FFFu + ((u >> 16) & 1u)) >> 16;   // RNE
    return (unsigned short)r;
}

// ---------------- fallback f32 -> xb bf16 ----------------
__global__ void k_copy_bf(const float4* __restrict__ src, uint2* __restrict__ dst, int n4) {
    int i = blockIdx.x * blockDim.x + threadIdx.x;
    if (i < n4) {
        float4 v = src[i];
        uint2 o;
        o.x = (unsigned)f2bf(v.x) | ((unsigned)f2bf(v.y) << 16);
        o.y = (unsigned)f2bf(v.z) | ((unsigned)f2bf(v.w) << 16);
        dst[i] = o;
    }
}

// ---------------- typed projection: xb[idx[m]] = bf16(feats[m] @ W + b) ----------------
__global__ void k_proj8(const float* __restrict__ feats, const float* __restrict__ W,
                        const float* __restrict__ bias, const int* __restrict__ idx,
                        unsigned short* __restrict__ xb, int M, int K) {
    __shared__ float lds[8 * 256];
    int m0 = blockIdx.x * 8;
    int rows = M - m0; if (rows > 8) rows = 8;
    for (int i = threadIdx.x; i < rows * K; i += 128) {
        int r = i / K, k = i - r * K;
        lds[r * K + k] = feats[(size_t)(m0 + r) * K + k];
    }
    __syncthreads();
    int o = threadIdx.x;  // 0..127 output col
    float bz = bias[o];
    float acc[8];
#pragma unroll
    for (int r = 0; r < 8; ++r) acc[r] = bz;
    for (int k = 0; k < K; ++k) {
        float wv = W[k * D + o];
#pragma unroll
        for (int r = 0; r < 8; ++r) acc[r] = fmaf(lds[r * K + k], wv, acc[r]);
    }
#pragma unroll
    for (int r = 0; r < 8; ++r) {
        if (r < rows) xb[(size_t)idx[m0 + r] * D + o] = f2bf(acc[r]);
    }
}

// ---------------- degree histogram (single atomic per edge) ----------------
__global__ void k_deg(const int* __restrict__ ei, int* __restrict__ deg, int E) {
    int e = blockIdx.x * blockDim.x + threadIdx.x;
    if (e < E) atomicAdd(&deg[ei[E + e]], 1);
}

// ---------------- exclusive scan (3 kernels) ----------------
#define SCAN_B 256
__global__ void k_scan1(const int* __restrict__ deg, int* __restrict__ off,
                        int* __restrict__ bsum, int n) {
    __shared__ int lds[SCAN_B];
    int i = blockIdx.x * SCAN_B + threadIdx.x;
    int v = (i < n) ? deg[i] : 0;
    lds[threadIdx.x] = v; __syncthreads();
    for (int s = 1; s < SCAN_B; s <<= 1) {
        int t = (threadIdx.x >= s) ? lds[threadIdx.x - s] : 0;
        __syncthreads();
        lds[threadIdx.x] += t;
        __syncthreads();
    }
    if (i < n) off[i] = lds[threadIdx.x] - v;  // exclusive
    if (threadIdx.x == SCAN_B - 1) bsum[blockIdx.x] = lds[threadIdx.x];
}
__global__ void k_scan2(int* __restrict__ bsum, int nb) {
    __shared__ int lds[SCAN_B];
    int v = (threadIdx.x < nb) ? bsum[threadIdx.x] : 0;
    lds[threadIdx.x] = v; __syncthreads();
    for (int s = 1; s < SCAN_B; s <<= 1) {
        int t = (threadIdx.x >= s) ? lds[threadIdx.x - s] : 0;
        __syncthreads();
        lds[threadIdx.x] += t;
        __syncthreads();
    }
    if (threadIdx.x < nb) bsum[threadIdx.x] = lds[threadIdx.x] - v;
}
__global__ void k_scan3(int* __restrict__ off, const int* __restrict__ bsum,
                        int* __restrict__ cursor, int n) {
    int i = blockIdx.x * SCAN_B + threadIdx.x;
    if (i < n) {
        int o = off[i] + bsum[blockIdx.x];
        off[i] = o;
        cursor[i] = o;
    }
}

// ---------------- CSR fill: csr[p] = src | etype<<16 ----------------
__global__ void k_fill(const int* __restrict__ ei, const int* __restrict__ et,
                       int* __restrict__ cursor, unsigned* __restrict__ csr, int E) {
    int e = blockIdx.x * blockDim.x + threadIdx.x;
    if (e < E) {
        int d = ei[E + e];
        int p = atomicAdd(&cursor[d], 1);
        csr[p] = (unsigned)ei[e] | ((unsigned)et[e] << 16);
    }
}

// ---------------- per-(node,relation) counts from CSR (no atomics) ----------------
// One node per wave; 10 ballots + popcount per 64-edge block; lane r writes cnt.
__global__ void k_cnt(const int* __restrict__ off, const int* __restrict__ deg,
                      const unsigned* __restrict__ csr, int* __restrict__ cntNR, int Nn) {
    int w = threadIdx.x >> 6, lane = threadIdx.x & 63;
    int n = blockIdx.x * 4 + w;
    if (n >= Nn) return;
    int start = off[n], dg = deg[n];
    const unsigned* cp = csr + start;
    int myCnt = 0;
    for (int j0 = 0; j0 < dg; j0 += 64) {
        int m = dg - j0; if (m > 64) m = 64;
        unsigned myU = (lane < m) ? cp[j0 + lane] : 0xFFFFFFFFu;  // sentinel et=0xFFFF
        int etl = (int)(myU >> 16);
#pragma unroll
        for (int r = 0; r < R_REL; ++r) {
            unsigned long long mask = __ballot(etl == r);
            if (lane == r) myCnt += __popcll(mask);
        }
    }
    if (lane < R_REL) cntNR[n * 16 + lane] = myCnt;
}

// ---------------- aggregation: Zb[n, b*128+d] = bf16( sum_r comp[r,b]*mean[r,n,d] ) ----
// One node per wave. Weighted-sum form: z[b] = sum_e (comp[et,b]/cnt[et]) * x[src].
// Counts precomputed (cntNR, from k_cnt). Weights lane-r-wise, fetched per edge via
// readlane (scalar data-indexing, no branches). 4-edge groups, 1-group-deep load
// pipeline (4 outstanding row loads). Sentinel-padded tails (et=63 -> weight 0).
__global__ void k_agg(const unsigned short* __restrict__ xb, const int* __restrict__ off,
                      const int* __restrict__ deg, const int* __restrict__ cntNR,
                      const unsigned* __restrict__ csr,
                      const float* __restrict__ comp, unsigned short* __restrict__ Zb, int Nn) {
    int w = threadIdx.x >> 6;
    int lane = threadIdx.x & 63;
    int n = blockIdx.x * 4 + w;
    if (n >= Nn) return;

    int start = off[n];
    int dg = deg[n];
    const unsigned* cp = csr + start;

    // lane r<10 holds w[b] = comp[r,b] * (cnt>0 ? 1/cnt : 1); lanes 10..63 hold 0
    float w0 = 0.f, w1 = 0.f, w2 = 0.f, w3 = 0.f;
    if (lane < R_REL) {
        int c = cntNR[n * 16 + lane];
        float inv = (c > 0) ? (1.f / (float)c) : 1.f;
        float4 c4 = *(const float4*)&comp[lane * NBASE];
        w0 = c4.x * inv; w1 = c4.y * inv; w2 = c4.z * inv; w3 = c4.w * inv;
    }

    float z0x = 0.f, z0y = 0.f, z1x = 0.f, z1y = 0.f;
    float z2x = 0.f, z2y = 0.f, z3x = 0.f, z3y = 0.f;

#define RL(i)  (unsigned)__builtin_amdgcn_readlane((int)myU, (i))
#define ROW(u) (((const unsigned*)(xb + (size_t)((u) & 0xFFFFu) * D))[lane])
#define PROC(uu, xx) { \
    int et = (int)((uu) >> 16); \
    float vx = __uint_as_float((xx) << 16); \
    float vy = __uint_as_float((xx) & 0xFFFF0000u); \
    float a0 = __uint_as_float((unsigned)__builtin_amdgcn_readlane((int)__float_as_uint(w0), et)); \
    float a1 = __uint_as_float((unsigned)__builtin_amdgcn_readlane((int)__float_as_uint(w1), et)); \
    float a2 = __uint_as_float((unsigned)__builtin_amdgcn_readlane((int)__float_as_uint(w2), et)); \
    float a3 = __uint_as_float((unsigned)__builtin_amdgcn_readlane((int)__float_as_uint(w3), et)); \
    z0x = fmaf(a0, vx, z0x); z0y = fmaf(a0, vy, z0y); \
    z1x = fmaf(a1, vx, z1x); z1y = fmaf(a1, vy, z1y); \
    z2x = fmaf(a2, vx, z2x); z2y = fmaf(a2, vy, z2y); \
    z3x = fmaf(a3, vx, z3x); z3y = fmaf(a3, vy, z3y); }

    for (int j0 = 0; j0 < dg; j0 += 64) {
        int m = dg - j0; if (m > 64) m = 64;
        // sentinel: src=0, et=63 -> zero weight, harmless L2-hot load
        unsigned myU = (lane < m) ? cp[j0 + lane] : 0x003F0000u;
        int mm = (m + 3) & ~3;

        unsigned ua0 = RL(0), ua1 = RL(1), ua2 = RL(2), ua3 = RL(3);
        unsigned xa0 = ROW(ua0), xa1 = ROW(ua1), xa2 = ROW(ua2), xa3 = ROW(ua3);

        for (int jj = 0; jj < mm; jj += 4) {
            unsigned ub0, ub1, ub2, ub3, xv0, xv1, xv2, xv3;
            bool more = (jj + 4) < mm;          // wave-uniform
            if (more) {                          // issue next group's 4 loads
                ub0 = RL(jj + 4); ub1 = RL(jj + 5); ub2 = RL(jj + 6); ub3 = RL(jj + 7);
                xv0 = ROW(ub0); xv1 = ROW(ub1); xv2 = ROW(ub2); xv3 = ROW(ub3);
            }
            PROC(ua0, xa0); PROC(ua1, xa1); PROC(ua2, xa2); PROC(ua3, xa3);
            if (more) {
                ua0 = ub0; ua1 = ub1; ua2 = ub2; ua3 = ub3;
                xa0 = xv0; xa1 = xv1; xa2 = xv2; xa3 = xv3;
            }
        }
    }
#undef RL
#undef ROW
#undef PROC

    unsigned short* zp = Zb + (size_t)n * 512 + lane * 2;
    *(unsigned*)(zp)       = (unsigned)f2bf(z0x) | ((unsigned)f2bf(z0y) << 16);
    *(unsigned*)(zp + 128) = (unsigned)f2bf(z1x) | ((unsigned)f2bf(z1y) << 16);
    *(unsigned*)(zp + 256) = (unsigned)f2bf(z2x) | ((unsigned)f2bf(z2y) << 16);
    *(unsigned*)(zp + 384) = (unsigned)f2bf(z3x) | ((unsigned)f2bf(z3y) << 16);
}

// ---------------- B panel transpose+cast: BT[n][k] = bf16([bases;root][k][n]) ----------
__global__ void k_bt(const float* __restrict__ bases, const float* __restrict__ root,
                     unsigned short* __restrict__ BT) {
    int i = blockIdx.x * 256 + threadIdx.x;       // over 128*640
    if (i >= 128 * 640) return;
    int n = i / 640, k = i - n * 640;
    float v = (k < 512) ? bases[(size_t)k * D + n] : root[(size_t)(k - 512) * D + n];
    BT[i] = f2bf(v);
}

// ---------------- MFMA layer GEMM: P = [Zb | xb] @ BT^T + bias ----------------
// M rows, K=640, N=128. BM=64, 256 threads = 4 waves, each wave 32x64.
// Double-buffered LDS, global->reg prefetch before MFMAs, ONE barrier per K-step.
// LDS rows padded to 80B (5 x 16B slots) -> <=2-way bank aliasing.
__global__ void k_gemm_mfma(const unsigned short* __restrict__ Zb,
                            const unsigned short* __restrict__ xb,
                            const unsigned short* __restrict__ BT,
                            const float* __restrict__ bias,
                            float* __restrict__ P, int M) {
    __shared__ unsigned short As[2][64 * 40];    // 10 KB
    __shared__ unsigned short Bs[2][128 * 40];   // 20.5 KB
    int t = threadIdx.x;
    int l = t & 63;
    int w = t >> 6;
    int wm = w & 1;               // 32-row half
    int wn = (w >> 1) * 64;       // 64-col half
    int m0 = blockIdx.x * 64;
    int lrow = l & 15;
    int kq = l >> 4;              // 0..3

    f32x4 acc[2][4];
#pragma unroll
    for (int s = 0; s < 2; ++s)
#pragma unroll
        for (int ct = 0; ct < 4; ++ct) acc[s][ct] = (f32x4){0.f, 0.f, 0.f, 0.f};

    // staging assignments: A 64x32 tile, 8 bf16 (16B) per thread
    int arow = t >> 2, ako = (t & 3) * 8;
    // B 128x32 tile, 16 bf16 (32B) per thread
    int brow = t >> 1, bko = (t & 1) * 16;
    int arg = m0 + arow; if (arg >= M) arg = M - 1;

    uint4 aR, bR0, bR1;
    auto gload = [&](int k0) {
        const unsigned short* asrc = (k0 < 512)
            ? &Zb[(size_t)arg * 512 + k0 + ako]
            : &xb[(size_t)arg * D + (k0 - 512) + ako];
        aR = *(const uint4*)asrc;
        const unsigned short* bsrc = &BT[(size_t)brow * 640 + k0 + bko];
        bR0 = *(const uint4*)bsrc;
        bR1 = *(const uint4*)(bsrc + 8);
    };
    auto sstore = [&](int p) {
        *(uint4*)&As[p][arow * 40 + ako] = aR;
        *(uint4*)&Bs[p][brow * 40 + bko] = bR0;
        *(uint4*)&Bs[p][brow * 40 + bko + 8] = bR1;
    };

    gload(0);
    sstore(0);
    int p = 0;
    for (int k0 = 0; k0 < 640; k0 += 32) {
        __syncthreads();                       // buf[p] ready for all waves
        if (k0 + 32 < 640) gload(k0 + 32);     // issue next-tile loads (overlap MFMA)
        short8 a0 = *(const short8*)&As[p][(wm * 32 + lrow) * 40 + kq * 8];
        short8 a1 = *(const short8*)&As[p][(wm * 32 + 16 + lrow) * 40 + kq * 8];
#pragma unroll
        for (int ct = 0; ct < 4; ++ct) {
            short8 b = *(const short8*)&Bs[p][(wn + ct * 16 + lrow) * 40 + kq * 8];
            acc[0][ct] = __builtin_amdgcn_mfma_f32_16x16x32_bf16(a0, b, acc[0][ct], 0, 0, 0);
            acc[1][ct] = __builtin_amdgcn_mfma_f32_16x16x32_bf16(a1, b, acc[1][ct], 0, 0, 0);
        }
        if (k0 + 32 < 640) { sstore(p ^ 1); p ^= 1; }
    }

    int r0 = m0 + wm * 32 + kq * 4;
#pragma unroll
    for (int sub = 0; sub < 2; ++sub) {
#pragma unroll
        for (int ct = 0; ct < 4; ++ct) {
            int col = wn + ct * 16 + lrow;
            float bv = bias[col];
#pragma unroll
            for (int r = 0; r < 4; ++r) {
                int rg = r0 + sub * 16 + r;
                if (rg < M) P[(size_t)rg * D + col] = acc[sub][ct][r] + bv;
            }
        }
    }
}

// ---------------- LayerNorm + ReLU -> bf16 ----------------
__global__ void k_lnrelu(const float* __restrict__ P, const float* __restrict__ g,
                         const float* __restrict__ b, unsigned short* __restrict__ hb, int Nn) {
    int w = threadIdx.x >> 6, lane = threadIdx.x & 63;
    int n = blockIdx.x * 4 + w;
    if (n >= Nn) return;
    float2 v = *(const float2*)&P[(size_t)n * D + lane * 2];
    float s = v.x + v.y;
#pragma unroll
    for (int o = 1; o < 64; o <<= 1) s += __shfl_xor(s, o, 64);
    float m = s * (1.f / 128.f);
    float dx = v.x - m, dy = v.y - m;
    float vs = dx * dx + dy * dy;
#pragma unroll
    for (int o = 1; o < 64; o <<= 1) vs += __shfl_xor(vs, o, 64);
    float inv = rsqrtf(vs * (1.f / 128.f) + LN_EPS);
    float2 gg = *(const float2*)&g[lane * 2];
    float2 bb = *(const float2*)&b[lane * 2];
    float ox = fmaxf(dx * inv * gg.x + bb.x, 0.f);
    float oy = fmaxf(dy * inv * gg.y + bb.y, 0.f);
    unsigned o2 = (unsigned)f2bf(ox) | ((unsigned)f2bf(oy) << 16);
    *(unsigned*)&hb[(size_t)n * D + lane * 2] = o2;
}

// ---------------- final: gather + LN + relu(h@Wc1+bc1) @ Wc2 + bc2 ----------------
__global__ void k_final(const float* __restrict__ P2, const int* __restrict__ nidx,
                        const float* __restrict__ g, const float* __restrict__ b,
                        const float* __restrict__ Wc1, const float* __restrict__ bc1,
                        const float* __restrict__ Wc2, const float* __restrict__ bc2,
                        float* __restrict__ out, int M) {
    __shared__ float ln[D];
    __shared__ float t[D];
    __shared__ float red[2];
    int i = blockIdx.x;
    if (i >= M) return;
    int d = threadIdx.x;
    int n = nidx[i];
    float v = P2[(size_t)n * D + d];
    float s = v;
#pragma unroll
    for (int o = 1; o < 64; o <<= 1) s += __shfl_xor(s, o, 64);
    if ((d & 63) == 0) red[d >> 6] = s;
    __syncthreads();
    float m = (red[0] + red[1]) * (1.f / 128.f);
    __syncthreads();
    float dv = v - m;
    float vs = dv * dv;
#pragma unroll
    for (int o = 1; o < 64; o <<= 1) vs += __shfl_xor(vs, o, 64);
    if ((d & 63) == 0) red[d >> 6] = vs;
    __syncthreads();
    float inv = rsqrtf((red[0] + red[1]) * (1.f / 128.f) + LN_EPS);
    ln[d] = dv * inv * g[d] + b[d];
    __syncthreads();
    float a = bc1[d];
    for (int k = 0; k < D; ++k) a = fmaf(ln[k], Wc1[k * D + d], a);
    t[d] = fmaxf(a, 0.f);
    __syncthreads();
    if (d < NC) {
        float o2 = bc2[d];
        for (int k = 0; k < D; ++k) o2 = fmaf(t[k], Wc2[k * NC + d], o2);
        out[(size_t)i * NC + d] = o2;
    }
}

extern "C" void kernel_launch(void* const* d_in, const int* in_sizes, int n_in,
                              void* d_out, int out_size, void* d_ws, size_t ws_size,
                              hipStream_t stream) {
    const int*   edge_index   = (const int*)d_in[0];
    const int*   edge_type    = (const int*)d_in[1];
    const int*   node_indices = (const int*)d_in[2];
    const float* file_feats   = (const float*)d_in[3];
    const int*   file_idx     = (const int*)d_in[4];
    const float* domain_feats = (const float*)d_in[5];
    const int*   domain_idx   = (const int*)d_in[6];
    const float* ip_feats     = (const float*)d_in[7];
    const int*   ip_idx       = (const int*)d_in[8];
    const float* fallback     = (const float*)d_in[9];
    const float* Wf = (const float*)d_in[10]; const float* bf = (const float*)d_in[11];
    const float* Wd = (const float*)d_in[12]; const float* bd = (const float*)d_in[13];
    const float* Wi = (const float*)d_in[14]; const float* bi = (const float*)d_in[15];
    const float* comp1 = (const float*)d_in[16]; const float* bases1 = (const float*)d_in[17];
    const float* root1 = (const float*)d_in[18]; const float* bias1 = (const float*)d_in[19];
    const float* comp2 = (const float*)d_in[20]; const float* bases2 = (const float*)d_in[21];
    const float* root2 = (const float*)d_in[22]; const float* bias2 = (const float*)d_in[23];
    const float* ln1g = (const float*)d_in[24]; const float* ln1b = (const float*)d_in[25];
    const float* ln2g = (const float*)d_in[26]; const float* ln2b = (const float*)d_in[27];
    const float* Wc1 = (const float*)d_in[28]; const float* bc1 = (const float*)d_in[29];
    const float* Wc2 = (const float*)d_in[30]; const float* bc2 = (const float*)d_in[31];

    const int E  = in_sizes[1];
    const int Nn = in_sizes[9] / D;
    const int Mf = in_sizes[4], Kf = in_sizes[3] / Mf;
    const int Md = in_sizes[6], Kd = in_sizes[5] / Md;
    const int Mi = in_sizes[8], Ki = in_sizes[7] / Mi;
    const int Msel = in_sizes[2];

    char* w = (char*)d_ws;
    auto alloc = [&](size_t bytes) {
        char* p = w;
        w += (bytes + 255) & ~(size_t)255;
        return p;
    };
    unsigned short* xb  = (unsigned short*)alloc((size_t)Nn * D * 2);   // 12.8 MB
    unsigned short* h1b = (unsigned short*)alloc((size_t)Nn * D * 2);   // 12.8 MB
    float*          P   = (float*)alloc((size_t)Nn * D * 4);            // 25.6 MB
    unsigned short* Zb  = (unsigned short*)alloc((size_t)Nn * 512 * 2); // 51.2 MB
    unsigned short* BT1 = (unsigned short*)alloc((size_t)128 * 640 * 2);
    unsigned short* BT2 = (unsigned short*)alloc((size_t)128 * 640 * 2);
    int* deg    = (int*)alloc((size_t)Nn * 4);
    int* cntNR  = (int*)alloc((size_t)Nn * 16 * 4);                     // 3.2 MB
    int* off    = (int*)alloc((size_t)Nn * 4);
    int* cursor = (int*)alloc((size_t)Nn * 4);
    int* bsum   = (int*)alloc(1024);
    unsigned* csr = (unsigned*)alloc((size_t)E * 4);                    // 3.2 MB

    hipMemsetAsync(deg, 0, (size_t)Nn * 4, stream);

    // node features (bf16)
    int n4 = Nn * D / 4;
    k_copy_bf<<<(n4 + 255) / 256, 256, 0, stream>>>((const float4*)fallback, (uint2*)xb, n4);
    k_proj8<<<(Mf + 7) / 8, 128, 0, stream>>>(file_feats, Wf, bf, file_idx, xb, Mf, Kf);
    k_proj8<<<(Md + 7) / 8, 128, 0, stream>>>(domain_feats, Wd, bd, domain_idx, xb, Md, Kd);
    k_proj8<<<(Mi + 7) / 8, 128, 0, stream>>>(ip_feats, Wi, bi, ip_idx, xb, Mi, Ki);

    // B panels (bf16, transposed)
    int nbt = (128 * 640 + 255) / 256;
    k_bt<<<nbt, 256, 0, stream>>>(bases1, root1, BT1);
    k_bt<<<nbt, 256, 0, stream>>>(bases2, root2, BT2);

    // CSR by dst (shared by both layers); cntNR derived from CSR (no atomics)
    k_deg<<<(E + 255) / 256, 256, 0, stream>>>(edge_index, deg, E);
    int nb = (Nn + SCAN_B - 1) / SCAN_B;
    k_scan1<<<nb, SCAN_B, 0, stream>>>(deg, off, bsum, Nn);
    k_scan2<<<1, SCAN_B, 0, stream>>>(bsum, nb);
    k_scan3<<<nb, SCAN_B, 0, stream>>>(off, bsum, cursor, Nn);
    k_fill<<<(E + 255) / 256, 256, 0, stream>>>(edge_index, edge_type, cursor, csr, E);
    k_cnt<<<(Nn + 3) / 4, 256, 0, stream>>>(off, deg, csr, cntNR, Nn);

    int gemmGrid = (Nn + 63) / 64;

    // layer 1
    k_agg<<<(Nn + 3) / 4, 256, 0, stream>>>(xb, off, deg, cntNR, csr, comp1, Zb, Nn);
    k_gemm_mfma<<<gemmGrid, 256, 0, stream>>>(Zb, xb, BT1, bias1, P, Nn);
    k_lnrelu<<<(Nn + 3) / 4, 256, 0, stream>>>(P, ln1g, ln1b, h1b, Nn);

    // layer 2
    k_agg<<<(Nn + 3) / 4, 256, 0, stream>>>(h1b, off, deg, cntNR, csr, comp2, Zb, Nn);
    k_gemm_mfma<<<gemmGrid, 256, 0, stream>>>(Zb, h1b, BT2, bias2, P, Nn);

    // head
    k_final<<<Msel, 128, 0, stream>>>(P, node_indices, ln2g, ln2b, Wc1, bc1, Wc2, bc2,
                                      (float*)d_out, Msel);
}